// Round 8
// baseline (418.971 us; speedup 1.0000x reference)
//
#include <hip/hip_runtime.h>
#include <hip/hip_bf16.h>

// R12: R11 + three bounded fixes.
// (1) proj reverted to the R9-proven decomposition (mt-major, z=0): R11's
//     z=bid&7 remap cost proj 43->48us and +11MiB writes.
// (2) softmax XCD-pinned to its S producer (z=bid&7, r=bid>>3): S chunk rows
//     written by XCD z are re-read on XCD z (L2 handoff), P lands in the L2
//     that z-pinned PV reads.
// (3) PV O16 stores nontemporal (written once, re-read only by streaming
//     tail) so the 16MiB write stream doesn't evict the per-XCD P+xT set.
// S/PV GEMM mapping, inner loop, buffer choreography: UNCHANGED from R11.
// Buffer timeline (MiB, out=64, ws=64: proj ws[0,32) xT ws[32,64)):
//   t1 transpose: x -> xT, x16(out[0,32))          t2 wcast: W16(out[32,34))
//   t3 proj GEMM: reads x16,W16 -> proj            [x16,W16 dead]
//   t4 S0 -> out[0,32) f32   t5 sm0: P0 -> out[32,48) dense   [S0 dead]
//   t6 S1 -> out[0,32)       t7 sm1: P1 -> out[48,64) dense   [S1 dead]
//   t8 PV01 (A=P0|P1): O16-01 -> out[0,16)                    [P0,P1 dead]
//   t9 S2 -> out[16,48)      t10 sm2: P2 -> out[48,64) dense  [S2 dead]
//   t11 S3 -> out[16,48)     [proj dead]  t12 sm3: P3 in-place lda4096
//   t13 PV23 (A=P2 lda2048 | P3 lda4096): O16-23 -> ws[0,16)  [xT,P2,P3 dead]
//   t14 copy out[0,16) -> ws[16,32)   t15 expand ws[0,32) -> out f32 [0,64)

typedef _Float16 f16;
typedef float f32x4 __attribute__((ext_vector_type(4)));
typedef _Float16 f16x8 __attribute__((ext_vector_type(8)));

#define MFMAH(A, B, C) __builtin_amdgcn_mfma_f32_16x16x32_f16((A), (B), (C), 0, 0, 0)

static constexpr int B_ = 8;
static constexpr int L_ = 2048;
static constexpr int D_ = 1024;
static constexpr int CH_ = 512;  // rows per batch per chunk

__device__ __forceinline__ void gload16(const f16* g, f16* l) {
  __builtin_amdgcn_global_load_lds(
      (const __attribute__((address_space(1))) void*)g,
      (__attribute__((address_space(3))) void*)l, 16, 0, 0);
}

// ---------------- K0: transpose x -> xT f16, plus x16 f16 ----------------
__global__ __launch_bounds__(256) void transpose_kernel(const float* __restrict__ x,
                                                        f16* __restrict__ xT,
                                                        f16* __restrict__ x16) {
  __shared__ f16 t[32][40];
  const int b = blockIdx.z;
  const int j0 = blockIdx.x << 5, d0 = blockIdx.y << 5;
  const int tid = threadIdx.x;
  const int r = tid >> 3, c = (tid & 7) << 2;
  float4 v = *(const float4*)&x[((size_t)(b * L_ + j0 + r)) * D_ + d0 + c];
  t[r][c + 0] = (f16)v.x; t[r][c + 1] = (f16)v.y;
  t[r][c + 2] = (f16)v.z; t[r][c + 3] = (f16)v.w;
  union { f16 h[4]; uint2 u; } xc;
  xc.h[0] = (f16)v.x; xc.h[1] = (f16)v.y;
  xc.h[2] = (f16)v.z; xc.h[3] = (f16)v.w;
  *(uint2*)&x16[((size_t)(b * L_ + j0 + r)) * D_ + d0 + c] = xc.u;
  __syncthreads();
  union { f16 h[4]; uint2 u; } o;
  o.h[0] = t[c + 0][r]; o.h[1] = t[c + 1][r];
  o.h[2] = t[c + 2][r]; o.h[3] = t[c + 3][r];
  *(uint2*)&xT[((size_t)(b * D_ + d0 + r)) * L_ + j0 + c] = o.u;
}

// ---------------- K0b: W f32 -> W16 ----------------
__global__ __launch_bounds__(256) void wcast_kernel(const float* __restrict__ W,
                                                    f16* __restrict__ W16) {
  const int i = (blockIdx.x * 256 + threadIdx.x) << 3;
  float4 a = *(const float4*)&W[i];
  float4 c = *(const float4*)&W[i + 4];
  union { f16 h[8]; uint4 u; } H;
  H.h[0] = (f16)a.x; H.h[1] = (f16)a.y; H.h[2] = (f16)a.z; H.h[3] = (f16)a.w;
  H.h[4] = (f16)c.x; H.h[5] = (f16)c.y; H.h[6] = (f16)c.z; H.h[7] = (f16)c.w;
  *(uint4*)&W16[i] = H.u;
}

// ---------------- Template GEMM: C = A(MxK) @ B(NxK)^T ----------------
// MODE 0: proj (bias+relu, f16 C), R9 decomposition: mt=bid%mTiles,
//         nt=bid/mTiles, z=0 -> bid%8 = mt%8 XCD locality on x16 panels.
// MODE 1: S chunk (f32 C, diag+mask), batch-pinned: z=bid&7.
// MODE 2: PV merged pair (f16 C, nontemporal), batch-pinned; per-block
//         A-source select: local m0<512 -> (A,lda), else (A1,lda1, m0-512).
template <int MODE>
__global__ __launch_bounds__(256, 2) void gemm128_kernel(
    const f16* __restrict__ A, const f16* __restrict__ A1,
    const f16* __restrict__ Bm, void* __restrict__ Cv,
    int lda, int lda1, int ldb, int ldc, int K, int mTiles,
    size_t aBatch, size_t a1Batch, size_t bBatch, size_t cBatch, int rowOff,
    const float* __restrict__ bias, const int* __restrict__ xmask) {
  const int bid = blockIdx.x;
  int z, mt, nt;
  if (MODE == 0) {
    z = 0;
    mt = bid % mTiles;
    nt = bid / mTiles;
  } else {
    z = bid & 7;
    const int rest = bid >> 3;
    mt = rest % mTiles;
    nt = rest / mTiles;
  }
  const int m0 = mt << 7, n0 = nt << 7;

  const f16* Ab;
  int ldA;
  if (MODE == 2 && m0 >= CH_) {
    Ab = A1 + (size_t)z * a1Batch + (size_t)(m0 - CH_) * lda1;
    ldA = lda1;
  } else {
    Ab = A + (size_t)z * aBatch + (size_t)m0 * lda;
    ldA = lda;
  }
  const f16* Bb = Bm + (size_t)z * bBatch;

  __shared__ f16 As[128 * 64], Bs[128 * 64];

  const int tid = threadIdx.x;
  const int w = tid >> 6, lane = tid & 63;
  const int wr = w >> 1, wc = w & 1;
  const int quad = lane >> 4, l16 = lane & 15;

  const int srow0 = w << 5;
  const int lrow = lane >> 3;   // 0..7
  const int lchunk = lane & 7;  // 16B chunk 0..7

  f32x4 acc[4][4];
#pragma unroll
  for (int i = 0; i < 4; ++i)
#pragma unroll
    for (int j = 0; j < 4; ++j) acc[i][j] = (f32x4){0.f, 0.f, 0.f, 0.f};

  for (int kc = 0; kc < K; kc += 64) {
#pragma unroll
    for (int u = 0; u < 4; ++u) {
      const int r = srow0 + (u << 3) + lrow;
      const int ca = (lchunk ^ (r & 7)) << 3;  // pre-swizzled source chunk
      gload16(&Ab[(size_t)r * ldA + kc + ca], &As[(srow0 + (u << 3)) << 6]);
      gload16(&Bb[(size_t)(n0 + r) * ldb + kc + ca], &Bs[(srow0 + (u << 3)) << 6]);
    }
    __syncthreads();  // drains vmcnt -> staged data visible

    f16x8 af[4], bf[4];
#pragma unroll
    for (int h = 0; h < 2; ++h) {
#pragma unroll
      for (int i = 0; i < 4; ++i) {
        const int ra = (wr << 6) + (i << 4) + l16;
        af[i] = *(const f16x8*)&As[(ra << 6) + ((((h << 2) + quad) ^ (ra & 7)) << 3)];
        const int rb = (wc << 6) + (i << 4) + l16;
        bf[i] = *(const f16x8*)&Bs[(rb << 6) + ((((h << 2) + quad) ^ (rb & 7)) << 3)];
      }
#pragma unroll
      for (int i = 0; i < 4; ++i)
#pragma unroll
        for (int j = 0; j < 4; ++j) acc[i][j] = MFMAH(af[i], bf[j], acc[i][j]);
    }
    __syncthreads();
  }

#pragma unroll
  for (int j = 0; j < 4; ++j) {
    const int n = n0 + (wc << 6) + (j << 4) + l16;
    float bv = 0.f;
    bool msk = false;
    if (MODE == 0) bv = bias[n];
    if (MODE == 1) msk = (xmask[z * L_ + n] != 0);
#pragma unroll
    for (int i = 0; i < 4; ++i) {
      const int mb = m0 + (wr << 6) + (i << 4) + (quad << 2);
#pragma unroll
      for (int r = 0; r < 4; ++r) {
        float v = acc[i][j][r];
        if (MODE == 1) {
          if (rowOff + mb + r == n) v = 0.f;  // diagonal zero
          if (msk) v = -1e30f;                // padding mask
          ((float*)Cv + (size_t)z * cBatch)[(size_t)(mb + r) * ldc + n] = v;
        } else if (MODE == 0) {
          ((f16*)Cv + (size_t)z * cBatch)[(size_t)(mb + r) * ldc + n] =
              (f16)fmaxf(v + bv, 0.f);
        } else {
          // O16 written once, re-read only by the streaming tail: nontemporal
          // so the write stream doesn't evict the per-XCD P+xT L2 set.
          union { f16 h; unsigned short u; } cvt;
          cvt.h = (f16)v;
          __builtin_nontemporal_store(
              cvt.u, (unsigned short*)&((f16*)Cv +
                                        (size_t)z * cBatch)[(size_t)(mb + r) * ldc + n]);
        }
      }
    }
  }
}

// ---------------- Row softmax: f32 row -> normalized f16 row at dst ----------------
// XCD-pinned to the S producer: z=bid&7 (same key as the S GEMM), r=bid>>3.
// dstStride in f16 elems: 2048 = dense buffer; 4096 = in-place compact.
__global__ __launch_bounds__(256) void softmax_kernel(const float* __restrict__ S,
                                                      f16* __restrict__ P,
                                                      int dstStride) {
  const int bid = blockIdx.x;
  const size_t row = (size_t)(bid & 7) * CH_ + (size_t)(bid >> 3);
  const float* Sp = S + row * 2048;
  f16* Pp = P + row * (size_t)dstStride;
  const int tid = threadIdx.x;
  const float4 sA = *(const float4*)&Sp[tid * 8];
  const float4 sB = *(const float4*)&Sp[tid * 8 + 4];
  float f[8];
  f[0] = sA.x; f[1] = sA.y; f[2] = sA.z; f[3] = sA.w;
  f[4] = sB.x; f[5] = sB.y; f[6] = sB.z; f[7] = sB.w;
  float mx = fmaxf(fmaxf(fmaxf(f[0], f[1]), fmaxf(f[2], f[3])),
                   fmaxf(fmaxf(f[4], f[5]), fmaxf(f[6], f[7])));
#pragma unroll
  for (int off = 1; off < 64; off <<= 1) mx = fmaxf(mx, __shfl_xor(mx, off));
  __shared__ float redm[4], reds[4];
  const int wv = tid >> 6;
  if ((tid & 63) == 0) redm[wv] = mx;
  __syncthreads();
  mx = fmaxf(fmaxf(redm[0], redm[1]), fmaxf(redm[2], redm[3]));
  float s = 0.f;
#pragma unroll
  for (int i = 0; i < 8; ++i) { f[i] = __expf(f[i] - mx); s += f[i]; }
#pragma unroll
  for (int off = 1; off < 64; off <<= 1) s += __shfl_xor(s, off);
  if ((tid & 63) == 0) reds[wv] = s;
  __syncthreads();
  s = (reds[0] + reds[1]) + (reds[2] + reds[3]);
  const float inv = 1.0f / s;
  f16x8 o;
#pragma unroll
  for (int i = 0; i < 8; ++i) o[i] = (f16)(f[i] * inv);
  *(f16x8*)&Pp[tid * 8] = o;
}

// ---------------- 16-MiB raw copy (uint4 granular) ----------------
__global__ __launch_bounds__(256) void copy16_kernel(const uint4* __restrict__ src,
                                                     uint4* __restrict__ dst) {
  const size_t i = (size_t)blockIdx.x * 256 + threadIdx.x;
  dst[i] = src[i];
}

// ---------------- Expand: O16 halves in ws -> out f32 ----------------
// ws f16 view: [0, 8M) = rows 1024..2047 (O16-23), [8M, 16M) = rows 0..1023
// (O16-01), each laid out [b][1024 rows][1024] f16.
__global__ __launch_bounds__(256) void expand_kernel(const f16* __restrict__ wsf,
                                                     float* __restrict__ out) {
  const size_t e = ((size_t)blockIdx.x * 256 + threadIdx.x) << 3;
  const int b = (int)(e >> 21);
  const int rem = (int)(e & ((1u << 21) - 1));
  const int r = rem >> 10;
  const int d = rem & 1023;
  const f16* src = (r < 1024)
      ? wsf + (8u << 20) + ((size_t)b << 20) + ((size_t)r << 10) + d
      : wsf + ((size_t)b << 20) + ((size_t)(r - 1024) << 10) + d;
  f16x8 v = *(const f16x8*)src;
  float4 a, c;
  a.x = (float)v[0]; a.y = (float)v[1]; a.z = (float)v[2]; a.w = (float)v[3];
  c.x = (float)v[4]; c.y = (float)v[5]; c.z = (float)v[6]; c.w = (float)v[7];
  *(float4*)&out[e] = a;
  *(float4*)&out[e + 4] = c;
}

extern "C" void kernel_launch(void* const* d_in, const int* in_sizes, int n_in,
                              void* d_out, int out_size, void* d_ws, size_t ws_size,
                              hipStream_t stream) {
  const float* x = (const float*)d_in[0];
  const int* xmask = (const int*)d_in[1];
  const float* W = (const float*)d_in[2];
  const float* bias = (const float*)d_in[3];
  float* out = (float*)d_out;

  const size_t elems = (size_t)B_ * L_ * D_;  // 16M
  if (ws_size < 2 * elems * sizeof(f16)) return;

  const size_t MiB = 1024 * 1024;
  f16* proj = (f16*)d_ws;                          // ws[0,32MiB)
  f16* xT = proj + elems;                          // ws[32,64MiB)
  f16* x16 = (f16*)d_out;                          // out[0,32MiB)
  f16* W16 = x16 + elems;                          // out[32,34MiB)
  float* Sf01 = (float*)d_out;                     // out[0,32MiB) f32 chunk
  float* Sf23 = (float*)((char*)d_out + 16 * MiB); // out[16,48MiB) f32 chunk
  f16* P0 = (f16*)((char*)d_out + 32 * MiB);       // dense [4096][2048]
  f16* P1 = (f16*)((char*)d_out + 48 * MiB);
  f16* P2 = P1;                                    // reuses P1 slot (dead)
  f16* P3 = (f16*)Sf23;                            // in-place, lda 4096
  f16* O01 = (f16*)d_out;                          // out[0,16MiB)
  f16* O23 = (f16*)d_ws;                           // ws[0,16MiB) (proj dead)

  transpose_kernel<<<dim3(L_ / 32, D_ / 32, B_), 256, 0, stream>>>(x, xT, x16);
  wcast_kernel<<<dim3((D_ * D_) / (256 * 8)), 256, 0, stream>>>(W, W16);

  // proj = relu(x16 @ W16^T + b): M=16384, N=1024, K=1024. R9 mapping:
  // mTiles=128 -> bid%8 = mt%8 (16 x16-panels + W16 per XCD). Proven 43us.
  gemm128_kernel<0><<<dim3(128 * (D_ / 128)), 256, 0, stream>>>(
      x16, nullptr, W16, (void*)proj, D_, 0, D_, D_, D_, 128,
      0, 0, 0, 0, 0, bias, nullptr);

  float* Sdst[4] = {Sf01, Sf01, Sf23, Sf23};
  f16* Pdst[4] = {P0, P1, P2, P3};
  for (int c = 0; c < 4; ++c) {
    // S chunk: M=512/batch (rows 512c..), N=2048, K=1024, Z=8, batch-pinned.
    gemm128_kernel<1><<<dim3(4 * 16 * 8), 256, 0, stream>>>(
        proj + (size_t)c * CH_ * D_, nullptr, proj, (void*)Sdst[c],
        D_, 0, D_, L_, D_, 4,
        (size_t)L_ * D_, 0, (size_t)L_ * D_, (size_t)CH_ * L_, c * CH_,
        nullptr, xmask);
    // softmax: 4096 rows, XCD-pinned to producer batch.
    softmax_kernel<<<dim3(B_ * CH_), 256, 0, stream>>>(
        Sdst[c], Pdst[c], c == 3 ? 2 * L_ : L_);
    if (c == 1) {
      // PV01: M=1024/batch over {P0,P1}, N=1024, K=2048, batch-pinned.
      gemm128_kernel<2><<<dim3(8 * 8 * 8), 256, 0, stream>>>(
          P0, P1, xT, (void*)O01, L_, L_, L_, D_, L_, 8,
          (size_t)CH_ * L_, (size_t)CH_ * L_, (size_t)D_ * L_, (size_t)1024 * D_,
          0, nullptr, nullptr);
    }
  }
  // PV23: A = P2 dense lda 2048 | P3 in-place lda 4096; O16-23 -> ws[0,16MiB).
  gemm128_kernel<2><<<dim3(8 * 8 * 8), 256, 0, stream>>>(
      P2, P3, xT, (void*)O23, L_, 2 * L_, L_, D_, L_, 8,
      (size_t)CH_ * L_, (size_t)CH_ * 2 * L_, (size_t)D_ * L_, (size_t)1024 * D_,
      0, nullptr, nullptr);

  // O16-01 out[0,16MiB) -> ws[16,32MiB), then one race-free expand ws -> out.
  copy16_kernel<<<dim3(4096), 256, 0, stream>>>(
      (const uint4*)O01, (uint4*)((char*)d_ws + 16 * MiB));
  expand_kernel<<<dim3((B_ * L_ * D_) / (256 * 8)), 256, 0, stream>>>(
      (const f16*)d_ws, out);
}